// Round 3
// baseline (1245.462 us; speedup 1.0000x reference)
//
#include <hip/hip_runtime.h>

#define NN 163842
#define NE 983040
#define NB 641   // ceil(NN/256)

// ---------------- degree count (int) ----------------
__global__ __launch_bounds__(256) void deg_count(const int* __restrict__ dst,
                                                 int* __restrict__ degi, int E) {
    int e = blockIdx.x * 256 + threadIdx.x;
    if (e < E) atomicAdd(&degi[dst[e]], 1);
}

// ---------------- exclusive scan of degi -> cursor (3 kernels) ----------------
__global__ __launch_bounds__(256) void scan1(const int* __restrict__ degi,
                                             int* __restrict__ cursor,
                                             int* __restrict__ bsum, int n) {
    __shared__ int tmp[256];
    int t = threadIdx.x;
    int i = blockIdx.x * 256 + t;
    int v = (i < n) ? degi[i] : 0;
    tmp[t] = v;
    __syncthreads();
    for (int o = 1; o < 256; o <<= 1) {
        int x = (t >= o) ? tmp[t - o] : 0;
        __syncthreads();
        tmp[t] += x;
        __syncthreads();
    }
    if (i < n) cursor[i] = tmp[t] - v;            // exclusive
    if (t == 255) bsum[blockIdx.x] = tmp[255];    // block total
}

__global__ void scan2(int* __restrict__ bsum, int nb) {
    __shared__ int tmp[1024];
    int t = threadIdx.x;
    int v = (t < nb) ? bsum[t] : 0;
    tmp[t] = v;
    __syncthreads();
    for (int o = 1; o < 1024; o <<= 1) {
        int x = (t >= o) ? tmp[t - o] : 0;
        __syncthreads();
        tmp[t] += x;
        __syncthreads();
    }
    if (t < nb) bsum[t] = tmp[t] - v;             // exclusive over block sums
}

__global__ __launch_bounds__(256) void scan3(int* __restrict__ cursor,
                                             const int* __restrict__ bsum, int n) {
    int i = blockIdx.x * 256 + threadIdx.x;
    if (i < n) cursor[i] += bsum[blockIdx.x];
}

// ---------------- scatter: permute src / edge_attr into dst-sorted order ----------------
// after this, cursor[d] = end-of-segment; start = cursor[d] - degi[d]
__global__ __launch_bounds__(256) void scatter_k(const int* __restrict__ src,
                                                 const int* __restrict__ dst,
                                                 const float* __restrict__ ea,
                                                 int* __restrict__ cursor,
                                                 int* __restrict__ srcs,
                                                 float2* __restrict__ eas2, int E) {
    int e = blockIdx.x * 256 + threadIdx.x;
    if (e >= E) return;
    int p = atomicAdd(&cursor[dst[e]], 1);
    srcs[p] = src[e];
    eas2[p] = make_float2(ea[2 * e], ea[2 * e + 1]);
}

// ---------------- pad x [N,22] -> xp [N,32] ----------------
__global__ __launch_bounds__(256) void pad_x(const float* __restrict__ x,
                                             float* __restrict__ xp, int n) {
    int t = blockIdx.x * 256 + threadIdx.x;
    if (t >= n * 32) return;
    int r = t >> 5, c = t & 31;
    xp[t] = (c < 22) ? x[r * 22 + c] : 0.0f;
}

// ---------------- gaussians in permuted order ----------------
__global__ __launch_bounds__(256) void gauss_p(const float2* __restrict__ eas2,
                                               const float* __restrict__ mu,
                                               const float* __restrict__ sigma,
                                               float* __restrict__ gs, int E) {
    int p = blockIdx.x * 256 + threadIdx.x;
    if (p >= E) return;
    float2 ea = eas2[p];
#pragma unroll
    for (int k = 0; k < 3; ++k) {
        float d0 = ea.x - mu[2 * k];
        float d1 = ea.y - mu[2 * k + 1];
        float s0 = sigma[2 * k];
        float s1 = sigma[2 * k + 1];
        float q  = d0 * d0 / (1e-15f + s0 * s0) + d1 * d1 / (1e-15f + s1 * s1);
        gs[3 * (long)p + k] = __expf(-0.5f * q);
    }
}

// ---------------- dst-centric segmented aggregation (no atomics) ----------------
// S[d, k, c] = (1/deg) * sum_{e in seg(d)} gs[e,k] * h[srcs[e], c]
template <int CINP>
__global__ __launch_bounds__(256) void aggregate(const float* __restrict__ h,
                                                 const int* __restrict__ srcs,
                                                 const float* __restrict__ gs,
                                                 const int* __restrict__ cursor,
                                                 const int* __restrict__ degi,
                                                 float* __restrict__ S, int n) {
    const int c  = threadIdx.x % CINP;
    const int sw = (blockIdx.x * 256 + threadIdx.x) / CINP;   // sub-wave id = node stream
    const int nsw = gridDim.x * (256 / CINP);
    for (int d = sw; d < n; d += nsw) {
        int end = cursor[d];
        int dg  = degi[d];
        float a0 = 0.0f, a1 = 0.0f, a2 = 0.0f;
        for (int p = end - dg; p < end; ++p) {
            int s = srcs[p];
            float g0 = gs[3 * p];
            float g1 = gs[3 * p + 1];
            float g2 = gs[3 * p + 2];
            float hv = h[(long)s * CINP + c];
            a0 = fmaf(g0, hv, a0);
            a1 = fmaf(g1, hv, a1);
            a2 = fmaf(g2, hv, a2);
        }
        float inv = 1.0f / (float)max(dg, 1);
        float* Sr = S + (long)d * (3 * CINP);
        Sr[c]            = a0 * inv;
        Sr[CINP + c]     = a1 * inv;
        Sr[2 * CINP + c] = a2 * inv;
    }
}

// ---------------- build combined weight Wc[4*CINP, COUT] = [g0;g1;g2;root] ----------------
template <int CIN, int CINP, int COUT>
__global__ __launch_bounds__(256) void build_wc(const float* __restrict__ g,
                                                const float* __restrict__ root,
                                                float* __restrict__ Wc) {
    int t = blockIdx.x * 256 + threadIdx.x;
    constexpr int KTOT = 4 * CINP;
    if (t >= KTOT * COUT) return;
    int kt = t / COUT, o = t % COUT;
    int k = kt / CINP, c = kt % CINP;
    float v = 0.0f;
    if (c < CIN) v = (k < 3) ? g[c * (3 * COUT) + k * COUT + o] : root[c * COUT + o];
    Wc[t] = v;
}

// ---------------- fused node GEMM: out = relu([S | h] @ Wc + b) ----------------
// K = 4*CINP split across lane halves (kh = lane>>5, 2*CINP each); 32 outputs/wave.
template <int CINP, int COUT>
__global__ __launch_bounds__(256, 2) void node_gemm(const float* __restrict__ S,
                                                    const float* __restrict__ h,
                                                    const float* __restrict__ Wc,
                                                    const float* __restrict__ bias,
                                                    float* __restrict__ out, int n) {
    constexpr int KH = 2 * CINP;
    constexpr int G  = COUT / 32;          // output groups per row (1 or 2)
    const int lane = threadIdx.x & 63;
    const int ol   = lane & 31;
    const int kh   = lane >> 5;
    const int wgid = blockIdx.x * 4 + (threadIdx.x >> 6);
    const int ob   = (wgid % G) * 32;
    const int o    = ob + ol;
    float w[KH];
#pragma unroll
    for (int i = 0; i < KH; ++i)
        w[i] = Wc[(kh * KH + i) * COUT + o];
    float b = bias[o];
    const int nstreams = (gridDim.x * 4) / G;
    for (int row = wgid / G; row < n; row += nstreams) {
        const float* Srow = S + (long)row * (3 * CINP);
        const float* hrow = h + (long)row * CINP;
        // lane's K range [kh*KH, kh*KH+KH): first CINP elems via pA, second CINP via pB
        const float* pA = Srow + kh * (2 * CINP);            // kh=0: S0 ; kh=1: S2
        const float* pB = kh ? hrow : (Srow + CINP);         // kh=0: S1 ; kh=1: h
        float acc = 0.0f;
#pragma unroll
        for (int i4 = 0; i4 < CINP / 4; ++i4) {
            float4 a = ((const float4*)pA)[i4];
            acc = fmaf(a.x, w[4 * i4 + 0], acc);
            acc = fmaf(a.y, w[4 * i4 + 1], acc);
            acc = fmaf(a.z, w[4 * i4 + 2], acc);
            acc = fmaf(a.w, w[4 * i4 + 3], acc);
        }
#pragma unroll
        for (int i4 = 0; i4 < CINP / 4; ++i4) {
            float4 a = ((const float4*)pB)[i4];
            acc = fmaf(a.x, w[CINP + 4 * i4 + 0], acc);
            acc = fmaf(a.y, w[CINP + 4 * i4 + 1], acc);
            acc = fmaf(a.z, w[CINP + 4 * i4 + 2], acc);
            acc = fmaf(a.w, w[CINP + 4 * i4 + 3], acc);
        }
        acc += __shfl_xor(acc, 32, 64);
        if (kh == 0)
            out[(long)row * COUT + o] = fmaxf(acc + b, 0.0f);
    }
}

// ---------------- final FC (64->2) + log_softmax ----------------
__global__ __launch_bounds__(256) void final_kernel(const float* __restrict__ h,
                                                    const float* __restrict__ fcw,
                                                    const float* __restrict__ fcb,
                                                    float* __restrict__ out, int n) {
    int i = blockIdx.x * 256 + threadIdx.x;
    if (i >= n) return;
    const float4* h4 = (const float4*)(h + (long)i * 64);
    float l0 = fcb[0];
    float l1 = fcb[1];
#pragma unroll
    for (int j4 = 0; j4 < 16; ++j4) {
        float4 hv = h4[j4];
        l0 = fmaf(hv.x, fcw[8 * j4 + 0], l0);
        l1 = fmaf(hv.x, fcw[8 * j4 + 1], l1);
        l0 = fmaf(hv.y, fcw[8 * j4 + 2], l0);
        l1 = fmaf(hv.y, fcw[8 * j4 + 3], l1);
        l0 = fmaf(hv.z, fcw[8 * j4 + 4], l0);
        l1 = fmaf(hv.z, fcw[8 * j4 + 5], l1);
        l0 = fmaf(hv.w, fcw[8 * j4 + 6], l0);
        l1 = fmaf(hv.w, fcw[8 * j4 + 7], l1);
    }
    float mx  = fmaxf(l0, l1);
    float lse = mx + logf(__expf(l0 - mx) + __expf(l1 - mx));
    out[2 * (long)i]     = l0 - lse;
    out[2 * (long)i + 1] = l1 - lse;
}

extern "C" void kernel_launch(void* const* d_in, const int* in_sizes, int n_in,
                              void* d_out, int out_size, void* d_ws, size_t ws_size,
                              hipStream_t stream) {
    const float* x   = (const float*)d_in[0];
    const int*   ei  = (const int*)d_in[1];
    const float* ea  = (const float*)d_in[2];
    const float* g_[3]  = {(const float*)d_in[3],  (const float*)d_in[8],  (const float*)d_in[13]};
    const float* mu_[3] = {(const float*)d_in[4],  (const float*)d_in[9],  (const float*)d_in[14]};
    const float* sg_[3] = {(const float*)d_in[5],  (const float*)d_in[10], (const float*)d_in[15]};
    const float* rt_[3] = {(const float*)d_in[6],  (const float*)d_in[11], (const float*)d_in[16]};
    const float* bs_[3] = {(const float*)d_in[7],  (const float*)d_in[12], (const float*)d_in[17]};
    const float* fcw = (const float*)d_in[18];
    const float* fcb = (const float*)d_in[19];
    float* out = (float*)d_out;
    (void)in_sizes; (void)n_in; (void)out_size; (void)ws_size;

    // workspace carve-up (~235 MB)
    char* w = (char*)d_ws;
    size_t off = 0;
    auto carve = [&](size_t bytes) -> void* {
        void* p = (void*)(w + off);
        off += (bytes + 255) & ~(size_t)255;
        return p;
    };
    int*    degi   = (int*)carve((size_t)NN * 4);
    int*    cursor = (int*)carve((size_t)NN * 4);
    int*    srcs   = (int*)carve((size_t)NE * 4);
    float2* eas2   = (float2*)carve((size_t)NE * 8);
    float*  gs     = (float*)carve((size_t)NE * 3 * 4);
    float*  S      = (float*)carve((size_t)NN * 192 * 4);
    int*    bsum   = (int*)carve(1024 * 4);
    float*  Wc     = (float*)carve((size_t)256 * 64 * 4);
    float*  hA     = (float*)carve((size_t)NN * 64 * 4);
    float*  hB     = (float*)carve((size_t)NN * 64 * 4);
    float*  xp     = S + (size_t)NN * 96;   // overlay: layers 0/1 use only S[0, NN*96)

    const int* src = ei;
    const int* dst = ei + NE;
    const int EB = (NE + 255) / 256;

    // ---- CSR build (once per call) ----
    hipMemsetAsync(degi, 0, (size_t)NN * 4, stream);
    deg_count<<<EB, 256, 0, stream>>>(dst, degi, NE);
    scan1<<<NB, 256, 0, stream>>>(degi, cursor, bsum, NN);
    scan2<<<1, 1024, 0, stream>>>(bsum, NB);
    scan3<<<NB, 256, 0, stream>>>(cursor, bsum, NN);
    scatter_k<<<EB, 256, 0, stream>>>(src, dst, ea, cursor, srcs, eas2, NE);
    pad_x<<<(NN * 32 + 255) / 256, 256, 0, stream>>>(x, xp, NN);

    // ---- layer 0: 22(pad 32) -> 32 ----
    gauss_p<<<EB, 256, 0, stream>>>(eas2, mu_[0], sg_[0], gs, NE);
    aggregate<32><<<1024, 256, 0, stream>>>(xp, srcs, gs, cursor, degi, S, NN);
    build_wc<22, 32, 32><<<(128 * 32 + 255) / 256, 256, 0, stream>>>(g_[0], rt_[0], Wc);
    node_gemm<32, 32><<<1024, 256, 0, stream>>>(S, xp, Wc, bs_[0], hA, NN);

    // ---- layer 1: 32 -> 64 ----
    gauss_p<<<EB, 256, 0, stream>>>(eas2, mu_[1], sg_[1], gs, NE);
    aggregate<32><<<1024, 256, 0, stream>>>(hA, srcs, gs, cursor, degi, S, NN);
    build_wc<32, 32, 64><<<(128 * 64 + 255) / 256, 256, 0, stream>>>(g_[1], rt_[1], Wc);
    node_gemm<32, 64><<<1024, 256, 0, stream>>>(S, hA, Wc, bs_[1], hB, NN);

    // ---- layer 2: 64 -> 64 ----
    gauss_p<<<EB, 256, 0, stream>>>(eas2, mu_[2], sg_[2], gs, NE);
    aggregate<64><<<2048, 256, 0, stream>>>(hB, srcs, gs, cursor, degi, S, NN);
    build_wc<64, 64, 64><<<(256 * 64 + 255) / 256, 256, 0, stream>>>(g_[2], rt_[2], Wc);
    node_gemm<64, 64><<<1024, 256, 0, stream>>>(S, hB, Wc, bs_[2], hA, NN);

    final_kernel<<<(NN + 255) / 256, 256, 0, stream>>>(hA, fcw, fcb, out, NN);
}